// Round 2
// baseline (2098.992 us; speedup 1.0000x reference)
//
#include <hip/hip_runtime.h>

#define WW 1280
#define HH 720
#define NB 8
#define NPIX (HH * WW)          // 921600
#define TOTAL (NB * NPIX)       // 7372800

// XCD-chunked block swizzle: contiguous 1/8 chunks of the grid per XCD
// (blockIdx%8 is the XCD round-robin heuristic). Identity if grid%8 != 0.
// Performance-only; correctness never depends on the mapping.
__device__ __forceinline__ int swz_bid() {
    int b = blockIdx.x;
    int n = gridDim.x;
    if ((n & 7) == 0) {
        int c = n >> 3;
        b = (b & 7) * c + (b >> 3);
    }
    return b;
}

// Decode source pixel -> footprint. Returns false if target out of bounds.
__device__ __forceinline__ bool decode(int i, const float* __restrict__ flow,
                                       const float* __restrict__ depth,
                                       int& base, int& g0, int& g1, int& g2, int& g3,
                                       float& fx, float& fy, int& db) {
    int b = i / NPIX;
    int p = i - b * NPIX;
    int y = p / WW;
    int x = p - y * WW;

    fx = flow[(size_t)b * 2 * NPIX + p];
    fy = flow[(size_t)b * 2 * NPIX + NPIX + p];
    db = __float_as_int(depth[i]);

    float x2 = (float)x + fx;
    float y2 = (float)y + fy;
    if (!(x2 >= 0.0f && y2 >= 0.0f && x2 <= (float)(WW - 1) && y2 <= (float)(HH - 1)))
        return false;

    int xL = min(max((int)floorf(x2), 0), WW - 1);
    int yT = min(max((int)floorf(y2), 0), HH - 1);
    int xR = min(xL + 1, WW - 1);
    int yB = min(yT + 1, HH - 1);

    base = b * NPIX;
    g0 = yT * WW + xL;
    g1 = yT * WW + xR;
    g2 = yB * WW + xL;
    g3 = yB * WW + xR;
    return true;
}

// ============================ packed path ============================
// ws = float4 per target pixel: {sumx, sumy, cnt, mind(bits)}

__global__ void kp_init(float4* __restrict__ ws4) {
    int i = blockIdx.x * blockDim.x + threadIdx.x;
    if (i < TOTAL) ws4[i] = make_float4(0.0f, 0.0f, 0.0f, 1e30f);
}

__global__ void kp_min(const float* __restrict__ flow,
                       const float* __restrict__ depth,
                       int* __restrict__ wsi) {
    int i = swz_bid() * blockDim.x + threadIdx.x;
    if (i >= TOTAL) return;
    int base, g0, g1, g2, g3, db; float fx, fy;
    if (!decode(i, flow, depth, base, g0, g1, g2, g3, fx, fy, db)) return;
    atomicMin(&wsi[(base + g0) * 4 + 3], db);
    atomicMin(&wsi[(base + g1) * 4 + 3], db);
    atomicMin(&wsi[(base + g2) * 4 + 3], db);
    atomicMin(&wsi[(base + g3) * 4 + 3], db);
}

__global__ void kp_add(const float* __restrict__ flow,
                       const float* __restrict__ depth,
                       float* __restrict__ wsf) {
    int i = swz_bid() * blockDim.x + threadIdx.x;
    if (i >= TOTAL) return;
    int base, g0, g1, g2, g3, db; float fx, fy;
    if (!decode(i, flow, depth, base, g0, g1, g2, g3, fx, fy, db)) return;
    const int* wsi = (const int*)wsf;
    int gs[4] = {g0, g1, g2, g3};
#pragma unroll
    for (int k = 0; k < 4; ++k) {
        int q = (base + gs[k]) * 4;
        if (wsi[q + 3] == db) {
            atomicAdd(&wsf[q + 0], -fx);
            atomicAdd(&wsf[q + 1], -fy);
            atomicAdd(&wsf[q + 2], 1.0f);
        }
    }
}

__global__ void kp_fin(const float4* __restrict__ ws4, float* __restrict__ out) {
    int i = blockIdx.x * blockDim.x + threadIdx.x;
    if (i >= TOTAL) return;
    int b = i / NPIX;
    int p = i - b * NPIX;
    float4 v = ws4[i];
    float inv = (v.z > 0.0f) ? 1.0f / v.z : 0.0f;
    size_t ox = (size_t)b * 2 * NPIX + p;
    out[ox]        = v.x * inv;
    out[ox + NPIX] = v.y * inv;
}

// ============================ fallback path (R0 layout + swizzle) ============
__global__ void kf_init(float* __restrict__ out, float* __restrict__ mind,
                        float* __restrict__ cnt) {
    int i = blockIdx.x * blockDim.x + threadIdx.x;
    if (i < 2 * TOTAL) out[i] = 0.0f;
    if (i < TOTAL) { mind[i] = 1e30f; cnt[i] = 0.0f; }
}

__global__ void kf_min(const float* __restrict__ flow,
                       const float* __restrict__ depth,
                       int* __restrict__ mind) {
    int i = swz_bid() * blockDim.x + threadIdx.x;
    if (i >= TOTAL) return;
    int base, g0, g1, g2, g3, db; float fx, fy;
    if (!decode(i, flow, depth, base, g0, g1, g2, g3, fx, fy, db)) return;
    atomicMin(&mind[base + g0], db);
    atomicMin(&mind[base + g1], db);
    atomicMin(&mind[base + g2], db);
    atomicMin(&mind[base + g3], db);
}

__global__ void kf_add(const float* __restrict__ flow,
                       const float* __restrict__ depth,
                       const int* __restrict__ mind,
                       float* __restrict__ out, float* __restrict__ cnt) {
    int i = swz_bid() * blockDim.x + threadIdx.x;
    if (i >= TOTAL) return;
    int base, g0, g1, g2, g3, db; float fx, fy;
    if (!decode(i, flow, depth, base, g0, g1, g2, g3, fx, fy, db)) return;
    int b = i / NPIX;
    float* outx = out + (size_t)b * 2 * NPIX;
    float* outy = outx + NPIX;
    int gs[4] = {g0, g1, g2, g3};
#pragma unroll
    for (int k = 0; k < 4; ++k) {
        int g = gs[k];
        if (mind[base + g] == db) {
            atomicAdd(&outx[g], -fx); atomicAdd(&outy[g], -fy);
            atomicAdd(&cnt[base + g], 1.0f);
        }
    }
}

__global__ void kf_fin(float* __restrict__ out, const float* __restrict__ cnt) {
    int i = blockIdx.x * blockDim.x + threadIdx.x;
    if (i >= TOTAL) return;
    int b = i / NPIX;
    int p = i - b * NPIX;
    float c = cnt[i];
    if (c > 0.0f) {
        size_t ox = (size_t)b * 2 * NPIX + p;
        float inv = 1.0f / c;
        out[ox] *= inv; out[ox + NPIX] *= inv;
    }
}

extern "C" void kernel_launch(void* const* d_in, const int* in_sizes, int n_in,
                              void* d_out, int out_size, void* d_ws, size_t ws_size,
                              hipStream_t stream) {
    const float* flow  = (const float*)d_in[0];
    const float* depth = (const float*)d_in[1];
    float* out = (float*)d_out;

    const int T = 256;
    const int G = (TOTAL + T - 1) / T;   // 28800, divisible by 8

    if (ws_size >= (size_t)TOTAL * 16) {
        float4* ws4 = (float4*)d_ws;
        kp_init<<<G, T, 0, stream>>>(ws4);
        kp_min <<<G, T, 0, stream>>>(flow, depth, (int*)ws4);
        kp_add <<<G, T, 0, stream>>>(flow, depth, (float*)ws4);
        kp_fin <<<G, T, 0, stream>>>(ws4, out);
    } else {
        float* mind = (float*)d_ws;
        float* cnt  = mind + TOTAL;
        kf_init<<<(2 * TOTAL + T - 1) / T, T, 0, stream>>>(out, mind, cnt);
        kf_min <<<G, T, 0, stream>>>(flow, depth, (int*)mind);
        kf_add <<<G, T, 0, stream>>>(flow, depth, (const int*)mind, out, cnt);
        kf_fin <<<G, T, 0, stream>>>(out, cnt);
    }
}

// Round 3
// 261.700 us; speedup vs baseline: 8.0206x; 8.0206x over previous
//
#include <hip/hip_runtime.h>

#define WW 1280
#define HH 720
#define NB 8
#define NPIX (HH * WW)          // 921600
#define TOTAL (NB * NPIX)       // 7372800

// ---- gather tiling ----
#define R 8                     // halo radius (covers |flow| < 6 with margin)
#define TH 48                   // tile height  (720 = 15*48)
#define TW 80                   // tile width   (1280 = 16*80)
#define WH (TH + 2*R)           // 64
#define WWIN (TW + 2*R)         // 96  (WH*WWIN = 6144 = 24*256)
#define TILES_X (WW / TW)       // 16
#define TILES_Y (HH / TH)       // 15
#define TPB (TILES_X * TILES_Y) // 240 tiles per batch
#define NT (NB * TPB)           // 1920 workgroups
#define TPIX (TH * TW)          // 3840 owned pixels (15*256)
#define CAP (1 << 20)           // outlier list capacity
#define FMAX_IN 6.0f            // |flow| < 6 -> inlier (corner offset within ±8)

// ---------------------------------------------------------------------------
// K0: init global mind = 1e30 bits, outlier count = 0.
// ---------------------------------------------------------------------------
__global__ void k0_init(int* __restrict__ mindG, int* __restrict__ nOutG) {
    int i = blockIdx.x * blockDim.x + threadIdx.x;
    if (i < TOTAL) mindG[i] = __float_as_int(1e30f);
    if (i == 0) *nOutG = 0;
}

// ---------------------------------------------------------------------------
// K1: outlier scan — sources with a valid target but |flow| >= 6 go to a list
// and contribute their depth-min via (rare) global atomics.
// ---------------------------------------------------------------------------
__global__ void k1_outlier_min(const float* __restrict__ flow,
                               const float* __restrict__ depth,
                               int* __restrict__ mindG,
                               int* __restrict__ nOutG, int* __restrict__ list) {
    int i = blockIdx.x * blockDim.x + threadIdx.x;
    if (i >= TOTAL) return;
    int b = i / NPIX, p = i - b * NPIX;
    int y = p / WW, x = p - y * WW;
    float fx = flow[(size_t)b * 2 * NPIX + p];
    float fy = flow[(size_t)b * 2 * NPIX + NPIX + p];
    float x2 = (float)x + fx, y2 = (float)y + fy;
    bool valid = (x2 >= 0.f && y2 >= 0.f && x2 <= (float)(WW-1) && y2 <= (float)(HH-1));
    if (!valid) return;
    if (fabsf(fx) < FMAX_IN && fabsf(fy) < FMAX_IN) return;   // inlier -> gather path
    int pos = atomicAdd(nOutG, 1);
    if (pos < CAP) list[pos] = i;
    int xL = min(max((int)floorf(x2), 0), WW - 1);
    int yT = min(max((int)floorf(y2), 0), HH - 1);
    int xR = min(xL + 1, WW - 1), yB = min(yT + 1, HH - 1);
    int db = __float_as_int(depth[i]);
    int base = b * NPIX;
    atomicMin(&mindG[base + yT * WW + xL], db);
    atomicMin(&mindG[base + yT * WW + xR], db);
    atomicMin(&mindG[base + yB * WW + xL], db);
    atomicMin(&mindG[base + yB * WW + xR], db);
}

// ---------------------------------------------------------------------------
// K2: gather. Each workgroup owns a TH x TW output tile. Two window scans:
// (A) LDS atomicMin of inlier depths; merge with global (outlier) mins;
// (B) gated LDS atomicAdd of (-fx,-fy,1). Plain-store owned pixels.
// If there are no outliers, divide and write final output directly.
// ---------------------------------------------------------------------------
__global__ void __launch_bounds__(256)
k2_gather(const float* __restrict__ flow, const float* __restrict__ depth,
          int* __restrict__ mindG, float* __restrict__ cntG,
          const int* __restrict__ nOutG, float* __restrict__ out) {
    __shared__ int   mind_t[TPIX];
    __shared__ float sx_t[TPIX];
    __shared__ float sy_t[TPIX];
    __shared__ float cn_t[TPIX];

    int bid = blockIdx.x;
    { int c = NT >> 3; bid = (bid & 7) * c + (bid >> 3); }   // XCD-chunked swizzle
    const int b   = bid / TPB;
    const int tt  = bid - b * TPB;
    const int tty = tt / TILES_X;
    const int ty0 = tty * TH;
    const int tx0 = (tt - tty * TILES_X) * TW;
    const int tid = threadIdx.x;
    const float* flowb  = flow  + (size_t)b * 2 * NPIX;
    const float* depthb = depth + (size_t)b * NPIX;

    const int IB = __float_as_int(1e30f);
    for (int k = tid; k < TPIX; k += 256) {
        mind_t[k] = IB; sx_t[k] = 0.f; sy_t[k] = 0.f; cn_t[k] = 0.f;
    }
    __syncthreads();

    // ---- phase A: window scan, LDS min ----
    for (int k = 0; k < (WH * WWIN) / 256; ++k) {
        int s  = k * 256 + tid;
        int wy = s / WWIN, wx = s - wy * WWIN;
        int gy = ty0 - R + wy, gx = tx0 - R + wx;
        if ((unsigned)gy >= HH || (unsigned)gx >= WW) continue;
        int p = gy * WW + gx;
        float fx = flowb[p], fy = flowb[p + NPIX];
        float x2 = (float)gx + fx, y2 = (float)gy + fy;
        if (!(x2 >= 0.f && y2 >= 0.f && x2 <= (float)(WW-1) && y2 <= (float)(HH-1))) continue;
        if (!(fabsf(fx) < FMAX_IN && fabsf(fy) < FMAX_IN)) continue;
        int xL = (int)floorf(x2), yT = (int)floorf(y2);
        int xR = min(xL + 1, WW - 1), yB = min(yT + 1, HH - 1);
        int db = __float_as_int(depthb[p]);
        int lyT = yT - ty0, lyB = yB - ty0, lxL = xL - tx0, lxR = xR - tx0;
        if ((unsigned)lyT < TH) {
            if ((unsigned)lxL < TW) atomicMin(&mind_t[lyT * TW + lxL], db);
            if ((unsigned)lxR < TW) atomicMin(&mind_t[lyT * TW + lxR], db);
        }
        if ((unsigned)lyB < TH) {
            if ((unsigned)lxL < TW) atomicMin(&mind_t[lyB * TW + lxL], db);
            if ((unsigned)lxR < TW) atomicMin(&mind_t[lyB * TW + lxR], db);
        }
    }
    __syncthreads();

    // ---- merge with global outlier mins; publish merged min ----
    for (int k = tid; k < TPIX; k += 256) {
        int ly = k / TW, lx = k - ly * TW;
        int g  = b * NPIX + (ty0 + ly) * WW + (tx0 + lx);
        int m  = min(mind_t[k], mindG[g]);   // positive floats: int min == float min
        mind_t[k] = m;
        mindG[g]  = m;
    }
    __syncthreads();

    // ---- phase B: window scan, gated LDS add ----
    for (int k = 0; k < (WH * WWIN) / 256; ++k) {
        int s  = k * 256 + tid;
        int wy = s / WWIN, wx = s - wy * WWIN;
        int gy = ty0 - R + wy, gx = tx0 - R + wx;
        if ((unsigned)gy >= HH || (unsigned)gx >= WW) continue;
        int p = gy * WW + gx;
        float fx = flowb[p], fy = flowb[p + NPIX];
        float x2 = (float)gx + fx, y2 = (float)gy + fy;
        if (!(x2 >= 0.f && y2 >= 0.f && x2 <= (float)(WW-1) && y2 <= (float)(HH-1))) continue;
        if (!(fabsf(fx) < FMAX_IN && fabsf(fy) < FMAX_IN)) continue;
        int xL = (int)floorf(x2), yT = (int)floorf(y2);
        int xR = min(xL + 1, WW - 1), yB = min(yT + 1, HH - 1);
        int db = __float_as_int(depthb[p]);
        int lyT = yT - ty0, lyB = yB - ty0, lxL = xL - tx0, lxR = xR - tx0;
        int ls[4] = {
            ((unsigned)lyT < TH && (unsigned)lxL < TW) ? lyT * TW + lxL : -1,
            ((unsigned)lyT < TH && (unsigned)lxR < TW) ? lyT * TW + lxR : -1,
            ((unsigned)lyB < TH && (unsigned)lxL < TW) ? lyB * TW + lxL : -1,
            ((unsigned)lyB < TH && (unsigned)lxR < TW) ? lyB * TW + lxR : -1 };
#pragma unroll
        for (int c = 0; c < 4; ++c) {
            int l = ls[c];
            if (l >= 0 && mind_t[l] == db) {
                atomicAdd(&sx_t[l], -fx);
                atomicAdd(&sy_t[l], -fy);
                atomicAdd(&cn_t[l], 1.0f);
            }
        }
    }
    __syncthreads();

    // ---- epilogue: plain-store owned pixels ----
    const int no = *nOutG;
    for (int k = tid; k < TPIX; k += 256) {
        int ly = k / TW, lx = k - ly * TW;
        int gy = ty0 + ly, gx = tx0 + lx;
        size_t ox = (size_t)b * 2 * NPIX + (size_t)gy * WW + gx;
        float c = cn_t[k], sxv = sx_t[k], syv = sy_t[k];
        if (no == 0) {
            float inv = (c > 0.f) ? 1.f / c : 0.f;   // final result directly
            out[ox]        = sxv * inv;
            out[ox + NPIX] = syv * inv;
        } else {
            out[ox]        = sxv;                     // raw sums; K3 adds, K4 divides
            out[ox + NPIX] = syv;
            cntG[b * NPIX + gy * WW + gx] = c;
        }
    }
}

// ---------------------------------------------------------------------------
// K3: outlier adds (gated on merged min), global atomics. No-op when list empty.
// ---------------------------------------------------------------------------
__global__ void k3_outlier_add(const float* __restrict__ flow,
                               const float* __restrict__ depth,
                               const int* __restrict__ mindG,
                               const int* __restrict__ nOutG,
                               const int* __restrict__ list,
                               float* __restrict__ out, float* __restrict__ cntG) {
    int n = min(*nOutG, CAP);
    for (int j = blockIdx.x * blockDim.x + threadIdx.x; j < n;
         j += gridDim.x * blockDim.x) {
        int i = list[j];
        int b = i / NPIX, p = i - b * NPIX;
        int y = p / WW, x = p - y * WW;
        float fx = flow[(size_t)b * 2 * NPIX + p];
        float fy = flow[(size_t)b * 2 * NPIX + NPIX + p];
        float x2 = (float)x + fx, y2 = (float)y + fy;
        int xL = min(max((int)floorf(x2), 0), WW - 1);
        int yT = min(max((int)floorf(y2), 0), HH - 1);
        int xR = min(xL + 1, WW - 1), yB = min(yT + 1, HH - 1);
        int db = __float_as_int(depth[i]);
        int base = b * NPIX;
        float* outx = out + (size_t)b * 2 * NPIX;
        float* outy = outx + NPIX;
        int gs[4] = { yT * WW + xL, yT * WW + xR, yB * WW + xL, yB * WW + xR };
#pragma unroll
        for (int c = 0; c < 4; ++c) {
            int g = gs[c];
            if (mindG[base + g] == db) {
                atomicAdd(&outx[g], -fx); atomicAdd(&outy[g], -fy);
                atomicAdd(&cntG[base + g], 1.0f);
            }
        }
    }
}

// ---------------------------------------------------------------------------
// K4: finalize divide — only needed when outliers existed.
// ---------------------------------------------------------------------------
__global__ void k4_fin(float* __restrict__ out, const float* __restrict__ cntG,
                       const int* __restrict__ nOutG) {
    if (*nOutG == 0) return;
    int i = blockIdx.x * blockDim.x + threadIdx.x;
    if (i >= TOTAL) return;
    int b = i / NPIX, p = i - b * NPIX;
    float c = cntG[i];
    if (c > 0.f) {
        size_t ox = (size_t)b * 2 * NPIX + p;
        float inv = 1.f / c;
        out[ox] *= inv; out[ox + NPIX] *= inv;
    }
}

// ======================= fallback (R0 scatter, validated) ====================
__device__ __forceinline__ bool decode(int i, const float* __restrict__ flow,
                                       const float* __restrict__ depth,
                                       int& base, int* gs, float& fx, float& fy, int& db) {
    int b = i / NPIX, p = i - b * NPIX;
    int y = p / WW, x = p - y * WW;
    fx = flow[(size_t)b * 2 * NPIX + p];
    fy = flow[(size_t)b * 2 * NPIX + NPIX + p];
    db = __float_as_int(depth[i]);
    float x2 = (float)x + fx, y2 = (float)y + fy;
    if (!(x2 >= 0.f && y2 >= 0.f && x2 <= (float)(WW-1) && y2 <= (float)(HH-1))) return false;
    int xL = min(max((int)floorf(x2), 0), WW - 1);
    int yT = min(max((int)floorf(y2), 0), HH - 1);
    int xR = min(xL + 1, WW - 1), yB = min(yT + 1, HH - 1);
    base = b * NPIX;
    gs[0] = yT * WW + xL; gs[1] = yT * WW + xR;
    gs[2] = yB * WW + xL; gs[3] = yB * WW + xR;
    return true;
}

__global__ void kf_init(float* __restrict__ out, float* __restrict__ mind,
                        float* __restrict__ cnt) {
    int i = blockIdx.x * blockDim.x + threadIdx.x;
    if (i < 2 * TOTAL) out[i] = 0.0f;
    if (i < TOTAL) { mind[i] = 1e30f; cnt[i] = 0.0f; }
}
__global__ void kf_min(const float* __restrict__ flow, const float* __restrict__ depth,
                       int* __restrict__ mind) {
    int i = blockIdx.x * blockDim.x + threadIdx.x;
    if (i >= TOTAL) return;
    int base, gs[4], db; float fx, fy;
    if (!decode(i, flow, depth, base, gs, fx, fy, db)) return;
#pragma unroll
    for (int c = 0; c < 4; ++c) atomicMin(&mind[base + gs[c]], db);
}
__global__ void kf_add(const float* __restrict__ flow, const float* __restrict__ depth,
                       const int* __restrict__ mind, float* __restrict__ out,
                       float* __restrict__ cnt) {
    int i = blockIdx.x * blockDim.x + threadIdx.x;
    if (i >= TOTAL) return;
    int base, gs[4], db; float fx, fy;
    if (!decode(i, flow, depth, base, gs, fx, fy, db)) return;
    int b = i / NPIX;
    float* outx = out + (size_t)b * 2 * NPIX;
    float* outy = outx + NPIX;
#pragma unroll
    for (int c = 0; c < 4; ++c) {
        int g = gs[c];
        if (mind[base + g] == db) {
            atomicAdd(&outx[g], -fx); atomicAdd(&outy[g], -fy);
            atomicAdd(&cnt[base + g], 1.0f);
        }
    }
}
__global__ void kf_fin(float* __restrict__ out, const float* __restrict__ cnt) {
    int i = blockIdx.x * blockDim.x + threadIdx.x;
    if (i >= TOTAL) return;
    int b = i / NPIX, p = i - b * NPIX;
    float c = cnt[i];
    if (c > 0.f) {
        size_t ox = (size_t)b * 2 * NPIX + p;
        float inv = 1.f / c;
        out[ox] *= inv; out[ox + NPIX] *= inv;
    }
}

extern "C" void kernel_launch(void* const* d_in, const int* in_sizes, int n_in,
                              void* d_out, int out_size, void* d_ws, size_t ws_size,
                              hipStream_t stream) {
    const float* flow  = (const float*)d_in[0];
    const float* depth = (const float*)d_in[1];
    float* out = (float*)d_out;

    const int T = 256;
    const int G = (TOTAL + T - 1) / T;   // 28800

    // ws layout: mindG[TOTAL] int | cntG[TOTAL] float | nOut int (64B pad) | list[CAP]
    size_t need = (size_t)TOTAL * 8 + 64 + (size_t)CAP * 4;
    if (ws_size >= need) {
        int*   mindG = (int*)d_ws;
        float* cntG  = (float*)(mindG + TOTAL);
        int*   nOutG = (int*)(cntG + TOTAL);
        int*   list  = nOutG + 16;
        k0_init<<<G, T, 0, stream>>>(mindG, nOutG);
        k1_outlier_min<<<G, T, 0, stream>>>(flow, depth, mindG, nOutG, list);
        k2_gather<<<NT, T, 0, stream>>>(flow, depth, mindG, cntG, nOutG, out);
        k3_outlier_add<<<128, T, 0, stream>>>(flow, depth, mindG, nOutG, list, out, cntG);
        k4_fin<<<G, T, 0, stream>>>(out, cntG, nOutG);
    } else {
        float* mind = (float*)d_ws;
        float* cnt  = mind + TOTAL;
        kf_init<<<(2 * TOTAL + T - 1) / T, T, 0, stream>>>(out, mind, cnt);
        kf_min <<<G, T, 0, stream>>>(flow, depth, (int*)mind);
        kf_add <<<G, T, 0, stream>>>(flow, depth, (const int*)mind, out, cnt);
        kf_fin <<<G, T, 0, stream>>>(out, cnt);
    }
}

// Round 4
// 162.718 us; speedup vs baseline: 12.8996x; 1.6083x over previous
//
#include <hip/hip_runtime.h>

#define WW 1280
#define HH 720
#define NB 8
#define NPIX (HH * WW)            // 921600
#define TOTAL (NB * NPIX)         // 7372800

#define FMAX 4.0f                 // |flow| < 4 -> inlier (corners within +/-4)
#define RHALO 4
#define TH 24                     // 720 = 30*24
#define TW 64                     // 1280 = 20*64
#define TPIX (TH * TW)            // 1536 -> 24KB LDS
#define TILES_X (WW / TW)         // 20
#define TILES_Y (HH / TH)         // 30
#define TPB (TILES_X * TILES_Y)   // 600
#define NT (NB * TPB)             // 4800 (divisible by 8)
#define WH (TH + 2 * RHALO)       // 32
#define WWIN (TW + 2 * RHALO)     // 72
#define GPR (WWIN / 4)            // 18 float4-groups per window row
#define NGRP (WH * GPR)           // 576
#define CAP (1 << 20)

// ---------------------------------------------------------------------------
// K1: build outlier list (valid target but |fx|>=4 or |fy|>=4). float4 scan.
// ---------------------------------------------------------------------------
__global__ void k1_outliers(const float* __restrict__ flow,
                            int* __restrict__ nOutG, int* __restrict__ list) {
    int i = blockIdx.x * blockDim.x + threadIdx.x;      // one float4 group
    int p4 = i * 4;
    int b = p4 / NPIX;
    int p = p4 - b * NPIX;
    int y = p / WW;
    int x0 = p - y * WW;
    const float* fb = flow + (size_t)b * 2 * NPIX;
    float4 fx4 = *(const float4*)&fb[p];
    float4 fy4 = *(const float4*)&fb[p + NPIX];
    float fxs[4] = {fx4.x, fx4.y, fx4.z, fx4.w};
    float fys[4] = {fy4.x, fy4.y, fy4.z, fy4.w};
#pragma unroll
    for (int j = 0; j < 4; ++j) {
        float fx = fxs[j], fy = fys[j];
        if (fabsf(fx) < FMAX && fabsf(fy) < FMAX) continue;          // inlier
        float x2 = (float)(x0 + j) + fx, y2 = (float)y + fy;
        if (!(x2 >= 0.f && y2 >= 0.f && x2 <= (float)(WW - 1) && y2 <= (float)(HH - 1)))
            continue;                                                 // invalid
        int pos = atomicAdd(nOutG, 1);
        if (pos < CAP) list[pos] = p4 + j;
    }
}

// ---------------------------------------------------------------------------
// K2: per-tile gather. All min/gate/add in LDS; outliers merged via list scan.
// Always divides in-kernel and plain-stores the owned tile.
// ---------------------------------------------------------------------------
__global__ void __launch_bounds__(256, 5)
k2_gather(const float* __restrict__ flow, const float* __restrict__ depth,
          const int* __restrict__ nOutG, const int* __restrict__ list,
          float* __restrict__ out) {
    __shared__ int   mind_t[TPIX];
    __shared__ float sx_t[TPIX];
    __shared__ float sy_t[TPIX];
    __shared__ float cn_t[TPIX];

    int bid = blockIdx.x;
    { const int c = NT >> 3; bid = (bid & 7) * c + (bid >> 3); }  // XCD swizzle
    const int b   = bid / TPB;
    const int tt  = bid - b * TPB;
    const int tty = tt / TILES_X;
    const int ty0 = tty * TH;
    const int tx0 = (tt - tty * TILES_X) * TW;
    const int tid = threadIdx.x;
    const float* flowb  = flow  + (size_t)b * 2 * NPIX;
    const float* depthb = depth + (size_t)b * NPIX;
    const int nOut = min(*nOutG, CAP);

    for (int k = tid; k < TPIX; k += 256) {
        mind_t[k] = __float_as_int(1e30f);
        sx_t[k] = 0.f; sy_t[k] = 0.f; cn_t[k] = 0.f;
    }
    __syncthreads();

    // ---- phase A: window scan, LDS min (float4 groups; groups are fully in
    // or fully out of bounds since TW, WW are multiples of 4) ----
    for (int g = tid; g < NGRP; g += 256) {
        int wy  = g / GPR;
        int gx0 = tx0 - RHALO + (g - wy * GPR) * 4;
        int gy  = ty0 - RHALO + wy;
        if ((unsigned)gy >= HH || (unsigned)gx0 >= WW) continue;
        int p = gy * WW + gx0;
        float4 fx4 = *(const float4*)&flowb[p];
        float4 fy4 = *(const float4*)&flowb[p + NPIX];
        float4 d4  = *(const float4*)&depthb[p];
        float fxs[4] = {fx4.x, fx4.y, fx4.z, fx4.w};
        float fys[4] = {fy4.x, fy4.y, fy4.z, fy4.w};
        float ds[4]  = {d4.x, d4.y, d4.z, d4.w};
#pragma unroll
        for (int j = 0; j < 4; ++j) {
            float fx = fxs[j], fy = fys[j];
            if (!(fabsf(fx) < FMAX && fabsf(fy) < FMAX)) continue;
            float x2 = (float)(gx0 + j) + fx, y2 = (float)gy + fy;
            if (!(x2 >= 0.f && y2 >= 0.f && x2 <= (float)(WW - 1) && y2 <= (float)(HH - 1)))
                continue;
            int xL = (int)floorf(x2), yT = (int)floorf(y2);
            int xR = min(xL + 1, WW - 1), yB = min(yT + 1, HH - 1);
            int db = __float_as_int(ds[j]);
            int lxL = xL - tx0, lxR = xR - tx0, lyT = yT - ty0, lyB = yB - ty0;
            if ((unsigned)lyT < TH) {
                if ((unsigned)lxL < TW) atomicMin(&mind_t[lyT * TW + lxL], db);
                if ((unsigned)lxR < TW) atomicMin(&mind_t[lyT * TW + lxR], db);
            }
            if ((unsigned)lyB < TH) {
                if ((unsigned)lxL < TW) atomicMin(&mind_t[lyB * TW + lxL], db);
                if ((unsigned)lxR < TW) atomicMin(&mind_t[lyB * TW + lxR], db);
            }
        }
    }
    // ---- outlier mins (tiny list, scanned by all blocks) ----
    for (int j = tid; j < nOut; j += 256) {
        int i = list[j];
        int ib = i / NPIX; if (ib != b) continue;
        int p = i - ib * NPIX;
        int y = p / WW, x = p - y * WW;
        float fx = flowb[p], fy = flowb[p + NPIX];
        float x2 = (float)x + fx, y2 = (float)y + fy;
        int xL = min(max((int)floorf(x2), 0), WW - 1);
        int yT = min(max((int)floorf(y2), 0), HH - 1);
        int xR = min(xL + 1, WW - 1), yB = min(yT + 1, HH - 1);
        int db = __float_as_int(depthb[p]);
        int lxL = xL - tx0, lxR = xR - tx0, lyT = yT - ty0, lyB = yB - ty0;
        if ((unsigned)lyT < TH) {
            if ((unsigned)lxL < TW) atomicMin(&mind_t[lyT * TW + lxL], db);
            if ((unsigned)lxR < TW) atomicMin(&mind_t[lyT * TW + lxR], db);
        }
        if ((unsigned)lyB < TH) {
            if ((unsigned)lxL < TW) atomicMin(&mind_t[lyB * TW + lxL], db);
            if ((unsigned)lxR < TW) atomicMin(&mind_t[lyB * TW + lxR], db);
        }
    }
    __syncthreads();

    // ---- phase B: window scan, gated LDS adds ----
    for (int g = tid; g < NGRP; g += 256) {
        int wy  = g / GPR;
        int gx0 = tx0 - RHALO + (g - wy * GPR) * 4;
        int gy  = ty0 - RHALO + wy;
        if ((unsigned)gy >= HH || (unsigned)gx0 >= WW) continue;
        int p = gy * WW + gx0;
        float4 fx4 = *(const float4*)&flowb[p];
        float4 fy4 = *(const float4*)&flowb[p + NPIX];
        float4 d4  = *(const float4*)&depthb[p];
        float fxs[4] = {fx4.x, fx4.y, fx4.z, fx4.w};
        float fys[4] = {fy4.x, fy4.y, fy4.z, fy4.w};
        float ds[4]  = {d4.x, d4.y, d4.z, d4.w};
#pragma unroll
        for (int j = 0; j < 4; ++j) {
            float fx = fxs[j], fy = fys[j];
            if (!(fabsf(fx) < FMAX && fabsf(fy) < FMAX)) continue;
            float x2 = (float)(gx0 + j) + fx, y2 = (float)gy + fy;
            if (!(x2 >= 0.f && y2 >= 0.f && x2 <= (float)(WW - 1) && y2 <= (float)(HH - 1)))
                continue;
            int xL = (int)floorf(x2), yT = (int)floorf(y2);
            int xR = min(xL + 1, WW - 1), yB = min(yT + 1, HH - 1);
            int db = __float_as_int(ds[j]);
            int lxL = xL - tx0, lxR = xR - tx0, lyT = yT - ty0, lyB = yB - ty0;
            int ls[4] = {
                ((unsigned)lyT < TH && (unsigned)lxL < TW) ? lyT * TW + lxL : -1,
                ((unsigned)lyT < TH && (unsigned)lxR < TW) ? lyT * TW + lxR : -1,
                ((unsigned)lyB < TH && (unsigned)lxL < TW) ? lyB * TW + lxL : -1,
                ((unsigned)lyB < TH && (unsigned)lxR < TW) ? lyB * TW + lxR : -1 };
#pragma unroll
            for (int c = 0; c < 4; ++c) {
                int l = ls[c];
                if (l >= 0 && mind_t[l] == db) {
                    atomicAdd(&sx_t[l], -fx);
                    atomicAdd(&sy_t[l], -fy);
                    atomicAdd(&cn_t[l], 1.0f);
                }
            }
        }
    }
    // ---- outlier adds ----
    for (int j = tid; j < nOut; j += 256) {
        int i = list[j];
        int ib = i / NPIX; if (ib != b) continue;
        int p = i - ib * NPIX;
        int y = p / WW, x = p - y * WW;
        float fx = flowb[p], fy = flowb[p + NPIX];
        float x2 = (float)x + fx, y2 = (float)y + fy;
        int xL = min(max((int)floorf(x2), 0), WW - 1);
        int yT = min(max((int)floorf(y2), 0), HH - 1);
        int xR = min(xL + 1, WW - 1), yB = min(yT + 1, HH - 1);
        int db = __float_as_int(depthb[p]);
        int lxL = xL - tx0, lxR = xR - tx0, lyT = yT - ty0, lyB = yB - ty0;
        int ls[4] = {
            ((unsigned)lyT < TH && (unsigned)lxL < TW) ? lyT * TW + lxL : -1,
            ((unsigned)lyT < TH && (unsigned)lxR < TW) ? lyT * TW + lxR : -1,
            ((unsigned)lyB < TH && (unsigned)lxL < TW) ? lyB * TW + lxL : -1,
            ((unsigned)lyB < TH && (unsigned)lxR < TW) ? lyB * TW + lxR : -1 };
#pragma unroll
        for (int c = 0; c < 4; ++c) {
            int l = ls[c];
            if (l >= 0 && mind_t[l] == db) {
                atomicAdd(&sx_t[l], -fx);
                atomicAdd(&sy_t[l], -fy);
                atomicAdd(&cn_t[l], 1.0f);
            }
        }
    }
    __syncthreads();

    // ---- epilogue: divide + plain-store owned tile ----
    for (int k = tid; k < TPIX; k += 256) {
        int ly = k / TW, lx = k - ly * TW;
        size_t ox = (size_t)b * 2 * NPIX + (size_t)(ty0 + ly) * WW + (tx0 + lx);
        float c = cn_t[k];
        float inv = (c > 0.f) ? 1.f / c : 0.f;
        out[ox]        = sx_t[k] * inv;
        out[ox + NPIX] = sy_t[k] * inv;
    }
}

extern "C" void kernel_launch(void* const* d_in, const int* in_sizes, int n_in,
                              void* d_out, int out_size, void* d_ws, size_t ws_size,
                              hipStream_t stream) {
    const float* flow  = (const float*)d_in[0];
    const float* depth = (const float*)d_in[1];
    float* out = (float*)d_out;

    int* nOutG = (int*)d_ws;
    int* list  = nOutG + 16;

    hipMemsetAsync(nOutG, 0, sizeof(int), stream);
    k1_outliers<<<TOTAL / 4 / 256, 256, 0, stream>>>(flow, nOutG, list);
    k2_gather  <<<NT, 256, 0, stream>>>(flow, depth, nOutG, list, out);
}

// Round 5
// 158.193 us; speedup vs baseline: 13.2685x; 1.0286x over previous
//
#include <hip/hip_runtime.h>

#define WW 1280
#define HH 720
#define NB 8
#define NPIX (HH * WW)            // 921600
#define TOTAL (NB * NPIX)         // 7372800

#define FMAX 4.0f                 // |flow| < 4 -> inlier (corners within +/-4)
#define RHALO 4
#define TH 24                     // 720 = 30*24
#define TW 64                     // 1280 = 20*64
#define TPIX (TH * TW)            // 1536 -> 24KB LDS
#define TILES_X (WW / TW)         // 20
#define TILES_Y (HH / TH)         // 30
#define TPB (TILES_X * TILES_Y)   // 600
#define NT (NB * TPB)             // 4800 (divisible by 8)
#define WH (TH + 2 * RHALO)       // 32
#define WWIN (TW + 2 * RHALO)     // 72
#define GPR (WWIN / 4)            // 18 float4-groups per window row
#define NGRP (WH * GPR)           // 576
#define NITER 3                   // ceil(NGRP/256)
#define CAPB 4096                 // per-batch outlier capacity (expect ~120)

// ---------------------------------------------------------------------------
// K1: build per-batch outlier lists (valid target but |fx|>=4 or |fy|>=4).
// Entry = {pixel, fx_bits, fy_bits, depth_bits} so K2 never reloads them.
// ---------------------------------------------------------------------------
__global__ void k1_outliers(const float* __restrict__ flow,
                            const float* __restrict__ depth,
                            int* __restrict__ nOut, int4* __restrict__ lists) {
    int i = blockIdx.x * blockDim.x + threadIdx.x;      // one float4 group
    int p4 = i * 4;
    int b = p4 / NPIX;
    int p = p4 - b * NPIX;
    int y = p / WW;
    int x0 = p - y * WW;
    const float* fb = flow + (size_t)b * 2 * NPIX;
    float4 fx4 = *(const float4*)&fb[p];
    float4 fy4 = *(const float4*)&fb[p + NPIX];
    float fxs[4] = {fx4.x, fx4.y, fx4.z, fx4.w};
    float fys[4] = {fy4.x, fy4.y, fy4.z, fy4.w};
#pragma unroll
    for (int j = 0; j < 4; ++j) {
        float fx = fxs[j], fy = fys[j];
        if (fabsf(fx) < FMAX && fabsf(fy) < FMAX) continue;          // inlier
        float x2 = (float)(x0 + j) + fx, y2 = (float)y + fy;
        if (!(x2 >= 0.f && y2 >= 0.f && x2 <= (float)(WW - 1) && y2 <= (float)(HH - 1)))
            continue;                                                 // invalid
        float d = depth[(size_t)b * NPIX + p + j];
        int pos = atomicAdd(&nOut[b], 1);
        if (pos < CAPB)
            lists[b * CAPB + pos] =
                make_int4(p + j, __float_as_int(fx), __float_as_int(fy), __float_as_int(d));
    }
}

// ---------------------------------------------------------------------------
// K2: per-tile gather, single window scan. Phase A loads window (float4),
// captures fx/fy/db in registers, does LDS atomicMin. Phase B replays from
// registers (zero global loads) doing gated LDS adds. Outliers merged from
// the per-batch list. Divide + plain-store the owned tile.
// ---------------------------------------------------------------------------
__global__ void __launch_bounds__(256, 6)
k2_gather(const float* __restrict__ flow, const float* __restrict__ depth,
          const int* __restrict__ nOut, const int4* __restrict__ lists,
          float* __restrict__ out) {
    __shared__ int   mind_t[TPIX];
    __shared__ float sx_t[TPIX];
    __shared__ float sy_t[TPIX];
    __shared__ float cn_t[TPIX];

    int bid = blockIdx.x;
    { const int c = NT >> 3; bid = (bid & 7) * c + (bid >> 3); }  // XCD swizzle
    const int b   = bid / TPB;
    const int tt  = bid - b * TPB;
    const int tty = tt / TILES_X;
    const int ty0 = tty * TH;
    const int tx0 = (tt - tty * TILES_X) * TW;
    const int tid = threadIdx.x;
    const float* flowb  = flow  + (size_t)b * 2 * NPIX;
    const float* depthb = depth + (size_t)b * NPIX;

    for (int k = tid; k < TPIX; k += 256) {
        mind_t[k] = __float_as_int(1e30f);
        sx_t[k] = 0.f; sy_t[k] = 0.f; cn_t[k] = 0.f;
    }
    __syncthreads();

    // ---- phase A: window scan (float4 groups), capture regs, LDS min ----
    float fxs[NITER][4], fys[NITER][4];
    int   dbs[NITER][4];
#pragma unroll
    for (int it = 0; it < NITER; ++it) {
        int g   = tid + it * 256;
        int wy  = g / GPR;
        int gx0 = tx0 - RHALO + (g - wy * GPR) * 4;
        int gy  = ty0 - RHALO + wy;
        if (g >= NGRP || (unsigned)gy >= HH || (unsigned)gx0 >= WW) continue;
        int p = gy * WW + gx0;
        float4 a = *(const float4*)&flowb[p];
        float4 c = *(const float4*)&flowb[p + NPIX];
        float4 d = *(const float4*)&depthb[p];
        fxs[it][0] = a.x; fxs[it][1] = a.y; fxs[it][2] = a.z; fxs[it][3] = a.w;
        fys[it][0] = c.x; fys[it][1] = c.y; fys[it][2] = c.z; fys[it][3] = c.w;
        dbs[it][0] = __float_as_int(d.x); dbs[it][1] = __float_as_int(d.y);
        dbs[it][2] = __float_as_int(d.z); dbs[it][3] = __float_as_int(d.w);
#pragma unroll
        for (int j = 0; j < 4; ++j) {
            float fx = fxs[it][j], fy = fys[it][j];
            if (!(fabsf(fx) < FMAX && fabsf(fy) < FMAX)) continue;
            float x2 = (float)(gx0 + j) + fx, y2 = (float)gy + fy;
            if (!(x2 >= 0.f && y2 >= 0.f && x2 <= (float)(WW - 1) && y2 <= (float)(HH - 1)))
                continue;
            int xL = (int)floorf(x2), yT = (int)floorf(y2);
            int xR = min(xL + 1, WW - 1), yB = min(yT + 1, HH - 1);
            int db = dbs[it][j];
            int lxL = xL - tx0, lxR = xR - tx0, lyT = yT - ty0, lyB = yB - ty0;
            if ((unsigned)lyT < TH) {
                if ((unsigned)lxL < TW) atomicMin(&mind_t[lyT * TW + lxL], db);
                if ((unsigned)lxR < TW) atomicMin(&mind_t[lyT * TW + lxR], db);
            }
            if ((unsigned)lyB < TH) {
                if ((unsigned)lxL < TW) atomicMin(&mind_t[lyB * TW + lxL], db);
                if ((unsigned)lxR < TW) atomicMin(&mind_t[lyB * TW + lxR], db);
            }
        }
    }
    // ---- outlier mins (per-batch list, self-contained entries) ----
    const int nb = min(nOut[b], CAPB);
    for (int j = tid; j < nb; j += 256) {
        int4 e = lists[b * CAPB + j];
        float fx = __int_as_float(e.y), fy = __int_as_float(e.z);
        int y = e.x / WW, x = e.x - y * WW;
        float x2 = (float)x + fx, y2 = (float)y + fy;
        int xL = min(max((int)floorf(x2), 0), WW - 1);
        int yT = min(max((int)floorf(y2), 0), HH - 1);
        int xR = min(xL + 1, WW - 1), yB = min(yT + 1, HH - 1);
        int lxL = xL - tx0, lxR = xR - tx0, lyT = yT - ty0, lyB = yB - ty0;
        if ((unsigned)lyT < TH) {
            if ((unsigned)lxL < TW) atomicMin(&mind_t[lyT * TW + lxL], e.w);
            if ((unsigned)lxR < TW) atomicMin(&mind_t[lyT * TW + lxR], e.w);
        }
        if ((unsigned)lyB < TH) {
            if ((unsigned)lxL < TW) atomicMin(&mind_t[lyB * TW + lxL], e.w);
            if ((unsigned)lxR < TW) atomicMin(&mind_t[lyB * TW + lxR], e.w);
        }
    }
    __syncthreads();

    // ---- phase B: replay from registers, gated LDS adds ----
#pragma unroll
    for (int it = 0; it < NITER; ++it) {
        int g   = tid + it * 256;
        int wy  = g / GPR;
        int gx0 = tx0 - RHALO + (g - wy * GPR) * 4;
        int gy  = ty0 - RHALO + wy;
        if (g >= NGRP || (unsigned)gy >= HH || (unsigned)gx0 >= WW) continue;
#pragma unroll
        for (int j = 0; j < 4; ++j) {
            float fx = fxs[it][j], fy = fys[it][j];
            if (!(fabsf(fx) < FMAX && fabsf(fy) < FMAX)) continue;
            float x2 = (float)(gx0 + j) + fx, y2 = (float)gy + fy;
            if (!(x2 >= 0.f && y2 >= 0.f && x2 <= (float)(WW - 1) && y2 <= (float)(HH - 1)))
                continue;
            int xL = (int)floorf(x2), yT = (int)floorf(y2);
            int xR = min(xL + 1, WW - 1), yB = min(yT + 1, HH - 1);
            int db = dbs[it][j];
            int lxL = xL - tx0, lxR = xR - tx0, lyT = yT - ty0, lyB = yB - ty0;
            int ls[4] = {
                ((unsigned)lyT < TH && (unsigned)lxL < TW) ? lyT * TW + lxL : -1,
                ((unsigned)lyT < TH && (unsigned)lxR < TW) ? lyT * TW + lxR : -1,
                ((unsigned)lyB < TH && (unsigned)lxL < TW) ? lyB * TW + lxL : -1,
                ((unsigned)lyB < TH && (unsigned)lxR < TW) ? lyB * TW + lxR : -1 };
#pragma unroll
            for (int c = 0; c < 4; ++c) {
                int l = ls[c];
                if (l >= 0 && mind_t[l] == db) {
                    atomicAdd(&sx_t[l], -fx);
                    atomicAdd(&sy_t[l], -fy);
                    atomicAdd(&cn_t[l], 1.0f);
                }
            }
        }
    }
    // ---- outlier adds ----
    for (int j = tid; j < nb; j += 256) {
        int4 e = lists[b * CAPB + j];
        float fx = __int_as_float(e.y), fy = __int_as_float(e.z);
        int y = e.x / WW, x = e.x - y * WW;
        float x2 = (float)x + fx, y2 = (float)y + fy;
        int xL = min(max((int)floorf(x2), 0), WW - 1);
        int yT = min(max((int)floorf(y2), 0), HH - 1);
        int xR = min(xL + 1, WW - 1), yB = min(yT + 1, HH - 1);
        int lxL = xL - tx0, lxR = xR - tx0, lyT = yT - ty0, lyB = yB - ty0;
        int ls[4] = {
            ((unsigned)lyT < TH && (unsigned)lxL < TW) ? lyT * TW + lxL : -1,
            ((unsigned)lyT < TH && (unsigned)lxR < TW) ? lyT * TW + lxR : -1,
            ((unsigned)lyB < TH && (unsigned)lxL < TW) ? lyB * TW + lxL : -1,
            ((unsigned)lyB < TH && (unsigned)lxR < TW) ? lyB * TW + lxR : -1 };
#pragma unroll
        for (int c = 0; c < 4; ++c) {
            int l = ls[c];
            if (l >= 0 && mind_t[l] == e.w) {
                atomicAdd(&sx_t[l], -fx);
                atomicAdd(&sy_t[l], -fy);
                atomicAdd(&cn_t[l], 1.0f);
            }
        }
    }
    __syncthreads();

    // ---- epilogue: divide + plain-store owned tile ----
    for (int k = tid; k < TPIX; k += 256) {
        int ly = k / TW, lx = k - ly * TW;
        size_t ox = (size_t)b * 2 * NPIX + (size_t)(ty0 + ly) * WW + (tx0 + lx);
        float c = cn_t[k];
        float inv = (c > 0.f) ? 1.f / c : 0.f;
        out[ox]        = sx_t[k] * inv;
        out[ox + NPIX] = sy_t[k] * inv;
    }
}

extern "C" void kernel_launch(void* const* d_in, const int* in_sizes, int n_in,
                              void* d_out, int out_size, void* d_ws, size_t ws_size,
                              hipStream_t stream) {
    const float* flow  = (const float*)d_in[0];
    const float* depth = (const float*)d_in[1];
    float* out = (float*)d_out;

    int*  nOut  = (int*)d_ws;                 // 16 ints (first NB used)
    int4* lists = (int4*)((char*)d_ws + 64);  // NB * CAPB entries

    hipMemsetAsync(nOut, 0, 64, stream);
    k1_outliers<<<TOTAL / 4 / 256, 256, 0, stream>>>(flow, depth, nOut, lists);
    k2_gather  <<<NT, 256, 0, stream>>>(flow, depth, nOut, lists, out);
}